// Round 5
// baseline (212.847 us; speedup 1.0000x reference)
//
#include <hip/hip_runtime.h>

// Inputs: [32,3,512,512] f32; pooled grid 128x128 per image.
#define HH 512
#define WW 512
#define PH 128
#define PW 128
#define CC 3

typedef float f32x4 __attribute__((ext_vector_type(4)));

// R9: revert to the best-measured structure (R6, 192.8us total, pool <=58.4us
// = >=3.45 TB/s delivered reads) with ONE change: plain cached loads instead
// of __builtin_nontemporal_load.
//
// Rationale: R7's counters proved ~half the 201MB read stream is served by
// Infinity Cache (FETCH_SIZE=98MB, each byte read once, L2=32MB). nt loads
// carry a no-allocate hint that suppresses LLC residency of the inputs
// across iterations; cached loads re-allocate them each iteration while the
// harness poison fills (streaming writes) only partially evict. Maximizing
// L3 hit fraction is the last untried lever on the read path: R7/R8 proved
// the clamp is shared downstream delivery (both VGPR-return and LDS-DMA
// paths = 73us in lockstep structure), and R6's flat structure is the
// fastest traversal of it.
//
// Kernel 1: g[b,i,j] = (1/48) * sum_{c, 4x4 block} (orig - enh)
__global__ void __launch_bounds__(256, 8)
pool_diff_kernel(const float* __restrict__ orig,
                 const float* __restrict__ enh,
                 float* __restrict__ g, int total) {
    const int idx = blockIdx.x * blockDim.x + threadIdx.x;
    if (idx >= total) return;
    const int j = idx & (PW - 1);
    const int i = (idx >> 7) & (PH - 1);
    const int b = idx >> 14;

    const size_t img  = (size_t)HH * WW;          // 262144
    const size_t base = (size_t)b * CC * img + (size_t)(i * 4) * WW + (size_t)(j * 4);

    f32x4 acc = {0.0f, 0.0f, 0.0f, 0.0f};
#pragma unroll
    for (int c = 0; c < CC; ++c) {
        const float* po = orig + base + (size_t)c * img;
        const float* pe = enh  + base + (size_t)c * img;
        // 8 cached dwordx4 loads in flight per channel; lanes 0..63 cover
        // 1KB contiguous per (c,r) pair -> fully coalesced.
        f32x4 o0 = *(const f32x4*)(po);
        f32x4 o1 = *(const f32x4*)(po + WW);
        f32x4 o2 = *(const f32x4*)(po + 2 * WW);
        f32x4 o3 = *(const f32x4*)(po + 3 * WW);
        f32x4 e0 = *(const f32x4*)(pe);
        f32x4 e1 = *(const f32x4*)(pe + WW);
        f32x4 e2 = *(const f32x4*)(pe + 2 * WW);
        f32x4 e3 = *(const f32x4*)(pe + 3 * WW);
        acc += (o0 - e0);
        acc += (o1 - e1);
        acc += (o2 - e2);
        acc += (o3 - e3);
    }
    const float s = (acc.x + acc.y) + (acc.z + acc.w);
    // Normal (caching) store: stencil_loss_kernel re-reads g, keep it in L2.
    g[idx] = s * (1.0f / 48.0f);
}

// Kernel 2: loss[i,j] = sum over {l,r,u,d} of (g[i,j] - g_pad[neighbor])^2
// Zero padding: out-of-bounds neighbor contributes 0 (so diff = g[i,j]).
__global__ void __launch_bounds__(256)
stencil_loss_kernel(const float* __restrict__ g,
                    float* __restrict__ out, int total) {
    int idx = blockIdx.x * blockDim.x + threadIdx.x;
    if (idx >= total) return;
    int j = idx & (PW - 1);
    int i = (idx >> 7) & (PH - 1);

    float c = g[idx];
    float l = (j > 0)      ? g[idx - 1]  : 0.0f;
    float r = (j < PW - 1) ? g[idx + 1]  : 0.0f;
    float u = (i > 0)      ? g[idx - PW] : 0.0f;
    float d = (i < PH - 1) ? g[idx + PW] : 0.0f;

    float dl = c - l, dr = c - r, du = c - u, dd = c - d;
    __builtin_nontemporal_store(dl * dl + dr * dr + du * du + dd * dd, out + idx);
}

extern "C" void kernel_launch(void* const* d_in, const int* in_sizes, int n_in,
                              void* d_out, int out_size, void* d_ws, size_t ws_size,
                              hipStream_t stream) {
    const float* orig = (const float*)d_in[0];
    const float* enh  = (const float*)d_in[1];
    float* out = (float*)d_out;
    float* g   = (float*)d_ws;  // 32*128*128 floats = 2 MB scratch

    const int batch = in_sizes[0] / (CC * HH * WW);   // 32
    const int total = batch * PH * PW;                // 524288

    const int block = 256;
    const int grid = (total + block - 1) / block;     // 2048

    // Flat full-occupancy grid: 8 blocks/CU resident at VGPR<=64.
    pool_diff_kernel<<<grid, block, 0, stream>>>(orig, enh, g, total);
    stencil_loss_kernel<<<grid, block, 0, stream>>>(g, out, total);
}

// Round 6
// 194.915 us; speedup vs baseline: 1.0920x; 1.0920x over previous
//
#include <hip/hip_runtime.h>

// Inputs: [32,3,512,512] f32; pooled grid 128x128 per image.
#define HH 512
#define WW 512
#define PH 128
#define PW 128
#define CC 3

typedef float f32x4 __attribute__((ext_vector_type(4)));

// R10 = R6 restored (best measured: 192.8us total; pool <=58.4us =
// >=3.45 TB/s delivered reads, the maximum across 10 structural variants).
//
// Why this exact configuration — each choice A/B-proven on this harness:
//  - nt loads, NOT cached (R9 A/B: cached = +14us; cached reads allocate
//    201MB/iter into an LLC full of dirty harness-poison lines -> dirty
//    writebacks steal HBM from the read stream; nt skips allocation while
//    still hitting the ~51% of lines that are L3-resident, FETCH=98MB).
//  - flat 2048-block grid, NOT persistent 512 (R0 A/B: 194.6 vs 192.8)
//    and NOT lockstep barrier-chunked (R7/R8: 73us pool, barriers
//    serialize what the flat form overlaps).
//  - VGPR-return path, NOT global_load_lds DMA (R8: identical 73us clamp
//    in lockstep form; no win from the LDS path).
//  - per-channel load-8/accumulate keeps live staging at 32 VGPR ->
//    VGPR_Count=32, 8 blocks/CU resident.
// Floor accounting: 118us harness fills + ~58us pool (read ceiling) +
// ~4us stencil + ~12us graph gaps ~= 192.5us.
__global__ void __launch_bounds__(256, 8)
pool_diff_kernel(const float* __restrict__ orig,
                 const float* __restrict__ enh,
                 float* __restrict__ g, int total) {
    const int idx = blockIdx.x * blockDim.x + threadIdx.x;
    if (idx >= total) return;
    const int j = idx & (PW - 1);
    const int i = (idx >> 7) & (PH - 1);
    const int b = idx >> 14;

    const size_t img  = (size_t)HH * WW;          // 262144
    const size_t base = (size_t)b * CC * img + (size_t)(i * 4) * WW + (size_t)(j * 4);

    f32x4 acc = {0.0f, 0.0f, 0.0f, 0.0f};
#pragma unroll
    for (int c = 0; c < CC; ++c) {
        const float* po = orig + base + (size_t)c * img;
        const float* pe = enh  + base + (size_t)c * img;
        // 8 nt dwordx4 loads in flight per channel; lanes 0..63 cover 1KB
        // contiguous per (c,r) pair -> fully coalesced.
        f32x4 o0 = __builtin_nontemporal_load((const f32x4*)(po));
        f32x4 o1 = __builtin_nontemporal_load((const f32x4*)(po + WW));
        f32x4 o2 = __builtin_nontemporal_load((const f32x4*)(po + 2 * WW));
        f32x4 o3 = __builtin_nontemporal_load((const f32x4*)(po + 3 * WW));
        f32x4 e0 = __builtin_nontemporal_load((const f32x4*)(pe));
        f32x4 e1 = __builtin_nontemporal_load((const f32x4*)(pe + WW));
        f32x4 e2 = __builtin_nontemporal_load((const f32x4*)(pe + 2 * WW));
        f32x4 e3 = __builtin_nontemporal_load((const f32x4*)(pe + 3 * WW));
        acc += (o0 - e0);
        acc += (o1 - e1);
        acc += (o2 - e2);
        acc += (o3 - e3);
    }
    const float s = (acc.x + acc.y) + (acc.z + acc.w);
    // Normal (caching) store: stencil_loss_kernel re-reads g, keep it in L2.
    g[idx] = s * (1.0f / 48.0f);
}

// Kernel 2: loss[i,j] = sum over {l,r,u,d} of (g[i,j] - g_pad[neighbor])^2
// Zero padding: out-of-bounds neighbor contributes 0 (so diff = g[i,j]).
__global__ void __launch_bounds__(256)
stencil_loss_kernel(const float* __restrict__ g,
                    float* __restrict__ out, int total) {
    int idx = blockIdx.x * blockDim.x + threadIdx.x;
    if (idx >= total) return;
    int j = idx & (PW - 1);
    int i = (idx >> 7) & (PH - 1);

    float c = g[idx];
    float l = (j > 0)      ? g[idx - 1]  : 0.0f;
    float r = (j < PW - 1) ? g[idx + 1]  : 0.0f;
    float u = (i > 0)      ? g[idx - PW] : 0.0f;
    float d = (i < PH - 1) ? g[idx + PW] : 0.0f;

    float dl = c - l, dr = c - r, du = c - u, dd = c - d;
    __builtin_nontemporal_store(dl * dl + dr * dr + du * du + dd * dd, out + idx);
}

extern "C" void kernel_launch(void* const* d_in, const int* in_sizes, int n_in,
                              void* d_out, int out_size, void* d_ws, size_t ws_size,
                              hipStream_t stream) {
    const float* orig = (const float*)d_in[0];
    const float* enh  = (const float*)d_in[1];
    float* out = (float*)d_out;
    float* g   = (float*)d_ws;  // 32*128*128 floats = 2 MB scratch

    const int batch = in_sizes[0] / (CC * HH * WW);   // 32
    const int total = batch * PH * PW;                // 524288

    const int block = 256;
    const int grid = (total + block - 1) / block;     // 2048

    // Flat full-occupancy grid: 8 blocks/CU resident at VGPR<=64.
    pool_diff_kernel<<<grid, block, 0, stream>>>(orig, enh, g, total);
    stencil_loss_kernel<<<grid, block, 0, stream>>>(g, out, total);
}